// Round 9
// baseline (233.220 us; speedup 1.0000x reference)
//
#include <hip/hip_runtime.h>
#include <math.h>

namespace {

constexpr int Bb = 16;
constexpr int Ll = 1024;
constexpr int Dd = 512;
constexpr int TOPK = 6;

typedef short  short8 __attribute__((ext_vector_type(8)));
typedef float  f32x4  __attribute__((ext_vector_type(4)));

__device__ __forceinline__ short f2bf(float x) {
  unsigned u = __builtin_bit_cast(unsigned, x);
  u += 0x7fffu + ((u >> 16) & 1u);          // RNE
  return (short)(u >> 16);
}
__device__ __forceinline__ float bf2f(short b) {
  unsigned u = ((unsigned)(unsigned short)b) << 16;
  return __builtin_bit_cast(float, u);
}
__device__ __forceinline__ void g2l16(const void* g, void* l) {
  __builtin_amdgcn_global_load_lds(
      (const __attribute__((address_space(1))) unsigned*)g,
      (__attribute__((address_space(3))) unsigned*)l, 16, 0, 0);
}
__device__ __forceinline__ short8 cvt8(float4 a, float4 b) {
  short8 o;
  o[0] = f2bf(a.x); o[1] = f2bf(a.y); o[2] = f2bf(a.z); o[3] = f2bf(a.w);
  o[4] = f2bf(b.x); o[5] = f2bf(b.y); o[6] = f2bf(b.z); o[7] = f2bf(b.w);
  return o;
}

// ===========================================================================
// NT GEMM, BM=128 x BN=64, BK=32, 256 thr (4 waves 2m x 2n, wave-tile 64x32,
// acc[4][2], 8 MFMA / K-step).  2-barrier loop with EARLY-ISSUE staging
// (next tile's loads go out between the ds_reads and the MFMA block).
// LDS XOR swizzle: unit = row*4 + (c8 ^ ((row>>1)&3)); slot read = hi.
//   [FIX vs r8: single k-slice per 32-col step — r8's ks*2+hi indexing
//    walked past the 4 slots/row and off the end of LDS -> NaN.]
// MODE 0 tiny : A fp32 (WK / WfcT), B bf16 (wqb / wvb) -> Gt / Ht   (64 blk)
// MODE 1 front: A fp32 (Q / V),     B bf16 (Gt / Ht)   -> T / U bf16
//               + 256 trailing blocks: K fp32 -> kb bf16            (2304 blk)
// MODE 2 corr : A = kb bf16 (rows s), B = T bf16 (rows t), split-K x2;
//               fused circular-diagonal reduce mv[z][(t-s)%1024]    (4096 blk)
// ===========================================================================
template<int MODE>
__global__ __launch_bounds__(256, 4) void gk(
    const void* __restrict__ A0, const void* __restrict__ A1,
    const short* __restrict__ B0, const short* __restrict__ B1,
    void* __restrict__ C0, void* __restrict__ C1,
    const float* __restrict__ KfIn, short* __restrict__ kbOut)
{
  __shared__ short lds[(MODE == 2) ? 12288 : 8192];
  __shared__ float bins[(MODE == 2) ? 192 : 1];

  const int tid = threadIdx.x;
  int z = 0, m0 = 0, n0 = 0, koff = 0;
  const float* Fa = nullptr;          // fp32 A (MODE 0/1)
  const short* Ab = nullptr;          // bf16 A (MODE 2)
  const short* Bp = nullptr;

  if (MODE == 0) {
    const int fb = blockIdx.x;
    z  = fb >> 5;
    m0 = ((fb >> 3) & 3) * 128;
    n0 = (fb & 7) * 64;
    Fa = (const float*)(z ? A1 : A0);
    Bp = z ? B1 : B0;
  } else if (MODE == 1) {
    const int fb = blockIdx.x;                   // 2304 = 8 x 288 (bijective)
    const int s  = (fb & 7) * 288 + (fb >> 3);
    if (s >= 2048) {                             // K fp32 -> bf16 copy slice
      const int ci = s - 2048;
#pragma unroll
      for (int it = 0; it < 16; ++it) {
        const size_t i8 = (size_t)(ci * 256 + tid) + (size_t)it * 65536;
        const float4 a = *(const float4*)(KfIn + i8 * 8);
        const float4 b = *(const float4*)(KfIn + i8 * 8 + 4);
        *(short8*)&kbOut[i8 * 8] = cvt8(a, b);
      }
      return;
    }
    z  = s >> 10;
    const int ss = s & 1023;
    m0 = (ss >> 3) * 128;
    n0 = (ss & 7) * 64;
    Fa = (const float*)(z ? A1 : A0);
    Bp = z ? B1 : B0;
  } else {
    const int fb = blockIdx.x;                   // 4096 = 8 x 512
    const int s  = (fb & 7) * 512 + (fb >> 3);
    z    = s >> 8;                               // batch
    koff = ((s >> 7) & 1) * 256;                 // K-half
    m0   = ((s >> 4) & 7) * 128;                 // kb row tile
    n0   = (s & 15) * 64;                        // T row tile
    Ab = (const short*)A0 + (size_t)z * Ll * Dd;
    Bp = B0 + (size_t)z * Ll * Dd;
  }

  // ---- staging maps ----
  // fp32 A (MODE 0/1): thread t -> row rP = t>>1, slots {2h, 2h+1}, h = t&1
  const int rP  = tid >> 1, hP = tid & 1;
  const int sxA = (rP >> 1) & 3;
  const int c80 = (hP * 2) ^ sxA, c81 = (hP * 2 + 1) ^ sxA;
  const int wA0 = (rP * 4 + hP * 2) * 8, wA1 = (rP * 4 + hP * 2 + 1) * 8;
  const float* gAf = (MODE != 2) ? Fa + (size_t)(m0 + rP) * Dd : nullptr;
  // bf16 A (MODE 2): units tid (rows 0..63) and 256+tid (rows 64..127)
  const int rS  = tid >> 2;
  const int c8S = (tid & 3) ^ ((rS >> 1) & 3);
  const short* gA2 = (MODE == 2) ? Ab + (size_t)(m0 + rS) * Dd + koff + c8S * 8 : nullptr;
  // B: unit tid, row rS (0..63)
  const short* gB = Bp + (size_t)(n0 + rS) * Dd + koff + c8S * 8;

  // ---- fragment read offsets (single k-slice: slot = hi) ----
  const int lane = tid & 63;
  const int wid  = tid >> 6;
  const int wr = wid >> 1, wn = wid & 1;
  const int lo = lane & 15, hi = lane >> 4;
  int aoff[4], boff[2];
#pragma unroll
  for (int i = 0; i < 4; ++i) {
    const int ar = wr * 64 + i * 16 + lo;
    aoff[i] = (ar * 4 + (hi ^ ((ar >> 1) & 3))) * 8;
  }
#pragma unroll
  for (int j = 0; j < 2; ++j) {
    const int br = wn * 32 + j * 16 + lo;
    boff[j] = (br * 4 + (hi ^ ((br >> 1) & 3))) * 8;
  }

  if (MODE == 2 && tid < 192) bins[tid] = 0.f;

  f32x4 acc[4][2];
#pragma unroll
  for (int i = 0; i < 4; ++i)
#pragma unroll
    for (int j = 0; j < 2; ++j) acc[i][j] = (f32x4){0.f, 0.f, 0.f, 0.f};

#define LDF(E, t) do { \
    E[0] = *(const float4*)(gAf + (t) * 32 + c80 * 8); \
    E[1] = *(const float4*)(gAf + (t) * 32 + c80 * 8 + 4); \
    E[2] = *(const float4*)(gAf + (t) * 32 + c81 * 8); \
    E[3] = *(const float4*)(gAf + (t) * 32 + c81 * 8 + 4); } while (0)
#define WRF(E) do { \
    *(short8*)&lds[wA0] = cvt8(E[0], E[1]); \
    *(short8*)&lds[wA1] = cvt8(E[2], E[3]); } while (0)
#define MFMA8(AB, BBASE) do { short8 a_[4], b_[2]; _Pragma("unroll") \
    for (int i_ = 0; i_ < 4; ++i_) a_[i_] = *(const short8*)&lds[(AB) + aoff[i_]]; \
    _Pragma("unroll") \
    for (int j_ = 0; j_ < 2; ++j_) b_[j_] = *(const short8*)&lds[(BBASE) + boff[j_]]; \
    ISSUE_NEXT; \
    _Pragma("unroll") \
    for (int i_ = 0; i_ < 4; ++i_) _Pragma("unroll") \
      for (int j_ = 0; j_ < 2; ++j_) \
        acc[i_][j_] = __builtin_amdgcn_mfma_f32_16x16x32_bf16(a_[i_], b_[j_], acc[i_][j_], 0, 0, 0); \
    } while (0)

  if (MODE != 2) {
    // ---- A fp32 single-buffer (reg-staged), B double-buffer ----
    float4 eA[4], eB[4];
    LDF(eA, 0);
    g2l16(gB, &lds[4096 + tid * 8]);            // B(0) -> p0
#pragma unroll 1
    for (int tt = 0; tt < 16; tt += 2) {
      {                                          // step tt  (p=0, cur=eA)
        WRF(eA);
        __syncthreads();
        const int t = tt;
#define ISSUE_NEXT do { if (t < 15) { LDF(eB, t + 1); \
        g2l16(gB + (t + 1) * 32, &lds[4096 + 2048 + tid * 8]); } } while (0)
        MFMA8(0, 4096);
#undef ISSUE_NEXT
        __syncthreads();
      }
      {                                          // step tt+1 (p=1, cur=eB)
        WRF(eB);
        __syncthreads();
        const int t = tt + 1;
#define ISSUE_NEXT do { if (t < 15) { LDF(eA, t + 1); \
        g2l16(gB + (t + 1) * 32, &lds[4096 + tid * 8]); } } while (0)
        MFMA8(0, 4096 + 2048);
#undef ISSUE_NEXT
        __syncthreads();
      }
    }
  } else {
    // ---- both operands bf16, A+B double-buffered, one barrier per step ----
#define STAGE2(t, p) do { \
    g2l16(gA2 + (t) * 32,                    &lds[(p) * 4096 + tid * 8]); \
    g2l16(gA2 + (size_t)64 * Dd + (t) * 32,  &lds[(p) * 4096 + 2048 + tid * 8]); \
    g2l16(gB  + (t) * 32,                    &lds[8192 + (p) * 2048 + tid * 8]); } while (0)
    STAGE2(0, 0);
    __syncthreads();
#pragma unroll 1
    for (int t = 0; t < 8; ++t) {
      const int p = t & 1;
#define ISSUE_NEXT do { if (t < 7) STAGE2(t + 1, p ^ 1); } while (0)
      MFMA8(p * 4096, 8192 + p * 2048);
#undef ISSUE_NEXT
      __syncthreads();
    }
#undef STAGE2
  }
#undef LDF
#undef WRF
#undef MFMA8

  // ---- epilogues ----
  if (MODE != 2) {
    short* C = (short*)(z ? C1 : C0);
#pragma unroll
    for (int i = 0; i < 4; ++i)
#pragma unroll
      for (int r = 0; r < 4; ++r) {
        const size_t row = m0 + wr * 64 + i * 16 + hi * 4 + r;
#pragma unroll
        for (int j = 0; j < 2; ++j)
          C[row * Dd + n0 + wn * 32 + j * 16 + lo] = f2bf(acc[i][j][r]);
      }
  } else {
    // d = t - s = n_loc - m_loc; bin = 127 + d in [0,190]
    float red[5][4];
#pragma unroll
    for (int g = 0; g < 5; ++g)
#pragma unroll
      for (int r = 0; r < 4; ++r) red[g][r] = 0.f;
#pragma unroll
    for (int i = 0; i < 4; ++i)
#pragma unroll
      for (int j = 0; j < 2; ++j)
#pragma unroll
        for (int r = 0; r < 4; ++r) red[j - i + 3][r] += acc[i][j][r];

    const int base = 127 + wn * 32 - wr * 64 + lo - 4 * hi;
#pragma unroll
    for (int g = 0; g < 5; ++g)
#pragma unroll
      for (int r = 0; r < 4; ++r)
        atomicAdd(&bins[base + 16 * (g - 3) - r], red[g][r]);
    __syncthreads();
    if (tid < 191) {
      float* mv = (float*)C0;
      const int l = (n0 - m0 + tid - 127) & (Ll - 1);
      atomicAdd(&mv[z * Ll + l], bins[tid]);
    }
  }
}

// ===========================================================================
// prep: z0: wqb = bf16(WQ) + zero mv; z1: wvb = bf16(WV);
//       z2: wtfF = fp32 transpose of Wfc.
// ===========================================================================
__global__ __launch_bounds__(256) void prep(
    const float* __restrict__ WQ, const float* __restrict__ WV,
    const float* __restrict__ Wfc,
    short* __restrict__ wqb, short* __restrict__ wvb,
    float* __restrict__ wtfF, float* __restrict__ mv)
{
  const int z = blockIdx.z;
  const int tx = threadIdx.x & 31, ty = threadIdx.x >> 5;
  const int bx = blockIdx.x, by = blockIdx.y;
  if (z < 2) {
    const float* W = z ? WV : WQ;
    short* O = z ? wvb : wqb;
#pragma unroll
    for (int s = 0; s < 32; s += 8) {
      const size_t o = (size_t)(by * 32 + ty + s) * 512 + bx * 32 + tx;
      O[o] = f2bf(W[o]);
    }
    if (z == 0 && threadIdx.x < 64) {
      const int fb = by * 16 + bx;
      mv[fb * 64 + threadIdx.x] = 0.f;
    }
  } else {
    __shared__ float t[32][33];
#pragma unroll
    for (int s = 0; s < 32; s += 8)
      t[ty + s][tx] = Wfc[(size_t)(by * 32 + ty + s) * 512 + bx * 32 + tx];
    __syncthreads();
#pragma unroll
    for (int s = 0; s < 32; s += 8)
      wtfF[(size_t)(bx * 32 + ty + s) * 512 + by * 32 + tx] = t[tx][ty + s];
  }
}

__global__ __launch_bounds__(1024) void topk_softmax(
    const float* __restrict__ mean_value,
    int* __restrict__ idx_out, float* __restrict__ w_out)
{
  __shared__ float vals[1024];
  __shared__ int   inds[1024];
  __shared__ float bm[1024];
  __shared__ int   topi[TOPK];
  const int t = threadIdx.x;
  float s = 0.f;
  for (int b = 0; b < Bb; ++b) s += mean_value[b * Ll + t];
  bm[t] = s;
  __syncthreads();
  for (int k = 0; k < TOPK; ++k) {
    bool taken = false;
    for (int j = 0; j < k; ++j) taken |= (topi[j] == t);
    vals[t] = taken ? -INFINITY : bm[t];
    inds[t] = t;
    __syncthreads();
    for (int stride = 512; stride > 0; stride >>= 1) {
      if (t < stride) {
        if (vals[t + stride] > vals[t]) { vals[t] = vals[t + stride]; inds[t] = inds[t + stride]; }
      }
      __syncthreads();
    }
    if (t == 0) topi[k] = inds[0];
    __syncthreads();
  }
  if (t < TOPK) idx_out[t] = topi[t];
  if (t < Bb) {
    float wv[TOPK], mx = -INFINITY;
#pragma unroll
    for (int k = 0; k < TOPK; ++k) {
      wv[k] = mean_value[t * Ll + topi[k]] * (1.f / 512.f);
      mx = fmaxf(mx, wv[k]);
    }
    float sum = 0.f;
#pragma unroll
    for (int k = 0; k < TOPK; ++k) { wv[k] = expf(wv[k] - mx); sum += wv[k]; }
#pragma unroll
    for (int k = 0; k < TOPK; ++k) w_out[t * TOPK + k] = wv[k] / sum;
  }
}

// out[b][l][c] = sum_k w[b][k] * bf2f(U[b][(l+idx_k)%L][c])   (fp32 out)
__global__ __launch_bounds__(256) void gather_out(
    const short* __restrict__ U, const float* __restrict__ w,
    const int* __restrict__ idx, float* __restrict__ out)
{
  const int b = blockIdx.y;
  __shared__ float ww[8];
  __shared__ int   ii[8];
  if (threadIdx.x < TOPK) { ww[threadIdx.x] = w[b * TOPK + threadIdx.x]; ii[threadIdx.x] = idx[threadIdx.x]; }
  __syncthreads();
  const int l = blockIdx.x * 4 + (threadIdx.x >> 6);
  const int c = (threadIdx.x & 63) * 8;
  const short* ub = U + (size_t)b * Ll * Dd;
  float a[8] = {};
#pragma unroll
  for (int k = 0; k < TOPK; ++k) {
    const short8 vv = *(const short8*)&ub[(size_t)((l + ii[k]) & (Ll - 1)) * Dd + c];
    const float wk = ww[k];
#pragma unroll
    for (int e = 0; e < 8; ++e) a[e] = fmaf(wk, bf2f(vv[e]), a[e]);
  }
  float* op = &out[((size_t)b * Ll + l) * Dd + c];
  *(float4*)op       = make_float4(a[0], a[1], a[2], a[3]);
  *(float4*)(op + 4) = make_float4(a[4], a[5], a[6], a[7]);
}

}  // namespace

extern "C" void kernel_launch(void* const* d_in, const int* in_sizes, int n_in,
                              void* d_out, int out_size, void* d_ws, size_t ws_size,
                              hipStream_t stream)
{
  const float* Q   = (const float*)d_in[0];
  const float* K   = (const float*)d_in[1];
  const float* V   = (const float*)d_in[2];
  const float* WQ  = (const float*)d_in[4];
  const float* WK  = (const float*)d_in[5];
  const float* WV  = (const float*)d_in[6];
  const float* Wfc = (const float*)d_in[7];
  float* out = (float*)d_out;

  char* ws = (char*)d_ws;
  const size_t SB = (size_t)Bb * Ll * Dd * sizeof(short);   // 16 MiB
  short* T    = (short*)(ws);
  short* U    = (short*)(ws + 1 * SB);
  short* kb   = (short*)(ws + 2 * SB);
  short* wqb  = (short*)(ws + 3 * SB);
  short* wvb  = wqb + 512 * 512;
  short* Gt   = wvb + 512 * 512;
  short* Ht   = Gt  + 512 * 512;
  float* wtfF = (float*)(Ht + 512 * 512);
  float* mv   = wtfF + 512 * 512;
  float* w    = mv + Bb * Ll;
  int*   idx  = (int*)(w + 128);

  // weights: wqb/wvb bf16, wtfF = Wfc^T fp32; zero mv
  prep<<<dim3(16, 16, 3), 256, 0, stream>>>(WQ, WV, Wfc, wqb, wvb, wtfF, mv);

  // Gt = WK @ wqb^T ; Ht = WfcT @ wvb^T   (bf16 out)
  gk<0><<<64, 256, 0, stream>>>(WK, wtfF, wqb, wvb, Gt, Ht, nullptr, nullptr);

  // T = bf16(Q @ Gt^T) ; U = bf16(V @ Ht^T) ; kb = bf16(K)
  gk<1><<<2304, 256, 0, stream>>>(Q, V, Gt, Ht, T, U, K, kb);

  // mv[b][(t-s)%L] += kb[b,s,:] · T[b,t,:]   (split-K x2, diag epilogue)
  gk<2><<<4096, 256, 0, stream>>>(kb, nullptr, T, nullptr, mv, nullptr, nullptr, nullptr);

  topk_softmax<<<1, 1024, 0, stream>>>(mv, idx, w);

  gather_out<<<dim3(Ll / 4, Bb), 256, 0, stream>>>(U, w, idx, out);
}

// Round 10
// 132.135 us; speedup vs baseline: 1.7650x; 1.7650x over previous
//
#include <hip/hip_runtime.h>
#include <math.h>

namespace {

constexpr int Bb = 16;
constexpr int Ll = 1024;
constexpr int Dd = 512;
constexpr int TOPK = 6;
constexpr int Kc = 512;

typedef short  short8 __attribute__((ext_vector_type(8)));
typedef float  f32x4  __attribute__((ext_vector_type(4)));

__device__ __forceinline__ short f2bf(float x) {
  unsigned u = __builtin_bit_cast(unsigned, x);
  u += 0x7fffu + ((u >> 16) & 1u);          // RNE
  return (short)(u >> 16);
}
__device__ __forceinline__ float bf2f(short b) {
  unsigned u = ((unsigned)(unsigned short)b) << 16;
  return __builtin_bit_cast(float, u);
}
__device__ __forceinline__ void g2l16(const void* g, void* l) {
  __builtin_amdgcn_global_load_lds(
      (const __attribute__((address_space(1))) unsigned*)g,
      (__attribute__((address_space(3))) unsigned*)l, 16, 0, 0);
}
__device__ __forceinline__ short8 cvt8(float4 a, float4 b) {
  short8 o;
  o[0] = f2bf(a.x); o[1] = f2bf(a.y); o[2] = f2bf(a.z); o[3] = f2bf(a.w);
  o[4] = f2bf(b.x); o[5] = f2bf(b.y); o[6] = f2bf(b.z); o[7] = f2bf(b.w);
  return o;
}

#define BARRIER() do { asm volatile("" ::: "memory"); \
    __builtin_amdgcn_s_barrier(); \
    asm volatile("" ::: "memory"); } while (0)
#define VMCNT8() asm volatile("s_waitcnt vmcnt(8)" ::: "memory")
#define VMCNT4() asm volatile("s_waitcnt vmcnt(4)" ::: "memory")
#define VMCNT0() asm volatile("s_waitcnt vmcnt(0)" ::: "memory")
#define LGKM0()  do { asm volatile("s_waitcnt lgkmcnt(0)" ::: "memory"); \
    __builtin_amdgcn_sched_barrier(0); } while (0)

// ===========================================================================
// r7's g64, modes 0/1 only (refcheck'd; front ~40 us = best measured):
// NT GEMM, 128x128 tile, BK=64 (8 K-steps), 256 thr (4 waves, 2m x 2n of
// 64x64), depth-2 LDS ring, counted entry-vmcnt, XOR-swizzled LDS.
// MODE 0: tiny — A,B bf16; C bf16.   z: 0 = Gt, 1 = Ht       (32 blocks)
// MODE 1: front — A fp32 (T14 split-stage + cvt), B bf16; C bf16.
//         z: 0 = T = Q@Gt^T, 1 = U = V@Ht^T                  (512 x 2 blocks)
// LDS swizzle: data(row, c8) at unit row*8 + (c8 ^ (row&7)); 16B units.
// ===========================================================================
template<int MODE>
__global__ __launch_bounds__(256) void g64(
    const void* __restrict__ A0, const void* __restrict__ A1,
    const short* __restrict__ B0, const short* __restrict__ B1,
    void* __restrict__ C0, void* __restrict__ C1)
{
  __shared__ short lds[2][16384];   // per buf: A [0,8192), B [8192,16384)

  const int tid = threadIdx.x;
  int z, m0, n0;
  if (MODE == 0) {
    z = blockIdx.x >> 4;
    const int s = blockIdx.x & 15;
    m0 = (s >> 2) * 128;  n0 = (s & 3) * 128;
  } else {
    z = blockIdx.z;
    const int fb = blockIdx.x;                 // 512, XCD chunk = 64
    const int s  = (fb & 7) * 64 + (fb >> 3);
    m0 = (s >> 2) * 128;  n0 = (s & 3) * 128;
  }

  // ---- staging source pointers (swizzled: c8S constant per thread) ----
  const int rS  = tid >> 3;                    // 0..31
  const int c8S = (tid & 7) ^ (rS & 7);        // source 16B-slot
  const short* Ga = nullptr;  const float* Fa = nullptr;
  const short* Gb = nullptr;
  if (MODE == 0) {
    Ga = (const short*)(z ? A1 : A0) + (size_t)(m0 + rS) * Kc + c8S * 8;
    Gb = (z ? B1 : B0) + (size_t)(n0 + rS) * Kc + c8S * 8;
  } else {
    Fa = (const float*)(z ? A1 : A0) + (size_t)(m0 + rS) * Kc + c8S * 8;
    Gb = (z ? B1 : B0) + (size_t)(n0 + rS) * Kc + c8S * 8;
  }

  // ---- fragment read offsets (per i and k-slice ks) ----
  const int lane = tid & 63;
  const int wid  = tid >> 6;
  const int wr = wid >> 1, wn = wid & 1;
  const int lo = lane & 15, hi = lane >> 4;
  int aoff[2][4], boff[2][4];
#pragma unroll
  for (int i = 0; i < 4; ++i) {
    const int ar = wr * 64 + i * 16 + lo;
    const int br = wn * 64 + i * 16 + lo;
#pragma unroll
    for (int ks = 0; ks < 2; ++ks) {
      aoff[ks][i] = (ar * 8 + ((ks * 4 + hi) ^ (ar & 7))) * 8;
      boff[ks][i] = 8192 + (br * 8 + ((ks * 4 + hi) ^ (br & 7))) * 8;
    }
  }

  f32x4 acc[4][4];
#pragma unroll
  for (int i = 0; i < 4; ++i)
#pragma unroll
    for (int j = 0; j < 4; ++j) acc[i][j] = (f32x4){0.f, 0.f, 0.f, 0.f};

#define SG_A(buf, kt) do { _Pragma("unroll") \
    for (int i_ = 0; i_ < 4; ++i_) \
      g2l16(Ga + (size_t)i_ * 32 * Kc + (kt) * 64, &lds[buf][(i_ * 256 + tid) * 8]); } while (0)
#define SG_B(buf, kt) do { _Pragma("unroll") \
    for (int i_ = 0; i_ < 4; ++i_) \
      g2l16(Gb + (size_t)i_ * 32 * Kc + (kt) * 64, &lds[buf][8192 + (i_ * 256 + tid) * 8]); } while (0)
#define LD_F(eV, F, kt) do { _Pragma("unroll") \
    for (int i_ = 0; i_ < 4; ++i_) { \
      eV[2 * i_]     = *(const float4*)((F) + (size_t)i_ * 32 * Kc + (kt) * 64); \
      eV[2 * i_ + 1] = *(const float4*)((F) + (size_t)i_ * 32 * Kc + (kt) * 64 + 4); } } while (0)
#define WR_F(buf, opb, eV) do { _Pragma("unroll") \
    for (int i_ = 0; i_ < 4; ++i_) \
      *(short8*)&lds[buf][(opb) + (i_ * 256 + tid) * 8] = cvt8(eV[2 * i_], eV[2 * i_ + 1]); } while (0)

  // ---- prologue: tile0 -> buf0, tile1 -> buf1 ----
  {
    float4 e[8];
    if (MODE == 1) {
      SG_B(0, 0); LD_F(e, Fa, 0); WR_F(0, 0, e);
      SG_B(1, 1); LD_F(e, Fa, 1); WR_F(1, 0, e);
    } else {
      SG_A(0, 0); SG_B(0, 0);
      SG_A(1, 1); SG_B(1, 1);
    }
  }

  int cur = 0;
#pragma unroll 1
  for (int t = 0; t < 8; ++t) {
    if (t == 7)            VMCNT0();
    else if (MODE == 0)    VMCNT8();
    else                   VMCNT4();
    LGKM0();
    BARRIER();

    const short* L = lds[cur];
    const bool pf = (t < 6);
    float4 e[8];

    short8 af[4], bq[4];
#pragma unroll
    for (int i = 0; i < 4; ++i) af[i] = *(const short8*)(L + aoff[0][i]);
#pragma unroll
    for (int j = 0; j < 4; ++j) bq[j] = *(const short8*)(L + boff[0][j]);
    if (pf && MODE == 1) LD_F(e, Fa, t + 2);
#pragma unroll
    for (int i = 0; i < 4; ++i)
#pragma unroll
      for (int j = 0; j < 4; ++j)
        acc[i][j] = __builtin_amdgcn_mfma_f32_16x16x32_bf16(af[i], bq[j], acc[i][j], 0, 0, 0);
#pragma unroll
    for (int i = 0; i < 4; ++i) af[i] = *(const short8*)(L + aoff[1][i]);
#pragma unroll
    for (int j = 0; j < 4; ++j) bq[j] = *(const short8*)(L + boff[1][j]);
#pragma unroll
    for (int i = 0; i < 4; ++i)
#pragma unroll
      for (int j = 0; j < 4; ++j)
        acc[i][j] = __builtin_amdgcn_mfma_f32_16x16x32_bf16(af[i], bq[j], acc[i][j], 0, 0, 0);

    BARRIER();   // all waves done reading buf cur -> safe to overwrite

    if (pf) {
      if (MODE == 1)      { SG_B(cur, t + 2); WR_F(cur, 0, e); }
      else                { SG_A(cur, t + 2); SG_B(cur, t + 2); }
    }
    cur ^= 1;
  }
#undef SG_A
#undef SG_B
#undef LD_F
#undef WR_F

  // ---- epilogue: bf16 C store ----
  short* C = (short*)(z ? C1 : C0);
#pragma unroll
  for (int i = 0; i < 4; ++i)
#pragma unroll
    for (int r = 0; r < 4; ++r) {
      const size_t row = m0 + wr * 64 + i * 16 + hi * 4 + r;
#pragma unroll
      for (int j = 0; j < 4; ++j)
        C[row * Dd + n0 + wn * 64 + j * 16 + lo] = f2bf(acc[i][j][r]);
    }
}

// ===========================================================================
// corr: per batch z, mv[z][(t-s)%1024] += T[z,t,:]·K[z,s,:].
// r6's validated 256x256 structure (1024 thr, 16 waves 4m x 4n of 64x64,
// BK=32, 2-slot dbuf, one barrier per K-step, 511-bin diag epilogue) with
// B = K read as fp32 and cvt'd during staging (no kb copy pass).
// LDS swizzle: unit = row*4 + (c8 ^ ((row>>1)&3)).
// L3-traffic model: (1 MB T + 2 MB K) x 4 re-reads x 16 batches = 192 MB.
// ===========================================================================
__global__ __launch_bounds__(1024) void corr_gemm(
    const short* __restrict__ T, const float* __restrict__ Kf,
    float* __restrict__ mv)
{
  __shared__ short lds[2][16384];        // per buf: A(T) [0,8192), B(K) [8192,16384)
  __shared__ float bins[512];

  const int tid = threadIdx.x;
  // chunk swizzle, chunk = 32: each XCD handles 2 whole batches (L2 residency)
  const int fb = blockIdx.x;
  const int s  = (fb & 7) * 32 + (fb >> 3);
  const int z  = s >> 4;
  const int m0 = ((s >> 2) & 3) * 256;   // T rows (t)
  const int n0 = (s & 3) * 256;          // K rows (s)

  const short* Ab = T  + (size_t)z * Ll * Dd;
  const float* Bf = Kf + (size_t)z * Ll * Dd;

  // staging: thread t -> unit t for both A and B (1024 units each)
  const int rS  = tid >> 2;
  const int c8S = (tid & 3) ^ ((rS >> 1) & 3);
  const short* gA = Ab + (size_t)(m0 + rS) * Dd + c8S * 8;
  const float* gB = Bf + (size_t)(n0 + rS) * Dd + c8S * 8;
  const int dB = 8192 + tid * 8;

  const int lane = tid & 63;
  const int wid  = tid >> 6;
  const int wm = wid >> 2, wn = wid & 3;
  const int lo = lane & 15, hi = lane >> 4;
  int aoff[4], boff[4];
#pragma unroll
  for (int i = 0; i < 4; ++i) {
    const int ar = wm * 64 + i * 16 + lo;
    aoff[i] = (ar * 4 + (hi ^ ((ar >> 1) & 3))) * 8;
  }
#pragma unroll
  for (int j = 0; j < 4; ++j) {
    const int br = wn * 64 + j * 16 + lo;
    boff[j] = 8192 + (br * 4 + (hi ^ ((br >> 1) & 3))) * 8;
  }

  if (tid < 512) bins[tid] = 0.f;

  f32x4 acc[4][4];
#pragma unroll
  for (int i = 0; i < 4; ++i)
#pragma unroll
    for (int j = 0; j < 4; ++j) acc[i][j] = (f32x4){0.f, 0.f, 0.f, 0.f};

  // prologue: k-tile 0 -> buf 0
  {
    g2l16(gA, &lds[0][tid * 8]);
    const float4 a = *(const float4*)(gB);
    const float4 b = *(const float4*)(gB + 4);
    *(short8*)&lds[0][dB] = cvt8(a, b);
  }
  __syncthreads();

#pragma unroll 1
  for (int t = 0; t < 16; ++t) {
    const int cur = t & 1;
    const short* L = &lds[cur][0];
    short8 af[4], bfr[4];
#pragma unroll
    for (int i = 0; i < 4; ++i) af[i]  = *(const short8*)(L + aoff[i]);
#pragma unroll
    for (int j = 0; j < 4; ++j) bfr[j] = *(const short8*)(L + boff[j]);

    float4 e0, e1;
    if (t < 15) {
      const int ke = (t + 1) * 32;
      g2l16(gA + ke, &lds[cur ^ 1][tid * 8]);
      e0 = *(const float4*)(gB + ke);
      e1 = *(const float4*)(gB + ke + 4);
    }

#pragma unroll
    for (int i = 0; i < 4; ++i)
#pragma unroll
      for (int j = 0; j < 4; ++j)
        acc[i][j] = __builtin_amdgcn_mfma_f32_16x16x32_bf16(af[i], bfr[j], acc[i][j], 0, 0, 0);

    if (t < 15) *(short8*)&lds[cur ^ 1][dB] = cvt8(e0, e1);
    __syncthreads();
  }

  // diagonal pre-reduce by (i-j, r), then LDS bins, then 511 global atomics
  float red[7][4];
#pragma unroll
  for (int d = 0; d < 7; ++d)
#pragma unroll
    for (int r = 0; r < 4; ++r) red[d][r] = 0.f;
#pragma unroll
  for (int i = 0; i < 4; ++i)
#pragma unroll
    for (int j = 0; j < 4; ++j)
#pragma unroll
      for (int r = 0; r < 4; ++r) red[i - j + 3][r] += acc[i][j][r];

  const int dbase = 255 + (wm - wn) * 64 + 4 * hi - lo;
#pragma unroll
  for (int d = 0; d < 7; ++d)
#pragma unroll
    for (int r = 0; r < 4; ++r)
      atomicAdd(&bins[dbase + 16 * (d - 3) + r], red[d][r]);
  __syncthreads();
  if (tid < 511) {
    const int l = (m0 - n0 + tid - 255) & (Ll - 1);
    atomicAdd(&mv[z * Ll + l], bins[tid]);
  }
}

// ===========================================================================
// prep: z in {0,1,2}: straight fp32->bf16 cvt of WQ/WK/WV (row layout kept);
// z==3: transposed cvt of Wfc (wtf[n][e] = Wfc[e][n]).  z==0 zeroes mv.
// ===========================================================================
__global__ __launch_bounds__(256) void prep(
    const float* __restrict__ WQ, const float* __restrict__ WK,
    const float* __restrict__ WV, const float* __restrict__ Wfc,
    short* __restrict__ wqb, short* __restrict__ wkb,
    short* __restrict__ wvb, short* __restrict__ wtf,
    float* __restrict__ mv)
{
  const int z = blockIdx.z;
  const int tx = threadIdx.x & 31, ty = threadIdx.x >> 5;
  const int bx = blockIdx.x, by = blockIdx.y;
  if (z < 3) {
    const float* W = (z == 0) ? WQ : (z == 1) ? WK : WV;
    short* O = (z == 0) ? wqb : (z == 1) ? wkb : wvb;
#pragma unroll
    for (int s = 0; s < 32; s += 8) {
      const size_t o = (size_t)(by * 32 + ty + s) * 512 + bx * 32 + tx;
      O[o] = f2bf(W[o]);
    }
    if (z == 0 && threadIdx.x < 64) {
      const int fb = by * 16 + bx;
      mv[fb * 64 + threadIdx.x] = 0.f;
    }
  } else {
    __shared__ float t[32][33];
#pragma unroll
    for (int s = 0; s < 32; s += 8)
      t[ty + s][tx] = Wfc[(size_t)(by * 32 + ty + s) * 512 + bx * 32 + tx];
    __syncthreads();
#pragma unroll
    for (int s = 0; s < 32; s += 8)
      wtf[(size_t)(bx * 32 + ty + s) * 512 + by * 32 + tx] = f2bf(t[tx][ty + s]);
  }
}

__global__ __launch_bounds__(1024) void topk_softmax(
    const float* __restrict__ mean_value,
    int* __restrict__ idx_out, float* __restrict__ w_out)
{
  __shared__ float vals[1024];
  __shared__ int   inds[1024];
  __shared__ float bm[1024];
  __shared__ int   topi[TOPK];
  const int t = threadIdx.x;
  float s = 0.f;
  for (int b = 0; b < Bb; ++b) s += mean_value[b * Ll + t];
  bm[t] = s;
  __syncthreads();
  for (int k = 0; k < TOPK; ++k) {
    bool taken = false;
    for (int j = 0; j < k; ++j) taken |= (topi[j] == t);
    vals[t] = taken ? -INFINITY : bm[t];
    inds[t] = t;
    __syncthreads();
    for (int stride = 512; stride > 0; stride >>= 1) {
      if (t < stride) {
        if (vals[t + stride] > vals[t]) { vals[t] = vals[t + stride]; inds[t] = inds[t + stride]; }
      }
      __syncthreads();
    }
    if (t == 0) topi[k] = inds[0];
    __syncthreads();
  }
  if (t < TOPK) idx_out[t] = topi[t];
  if (t < Bb) {
    float wv[TOPK], mx = -INFINITY;
#pragma unroll
    for (int k = 0; k < TOPK; ++k) {
      wv[k] = mean_value[t * Ll + topi[k]] * (1.f / 512.f);
      mx = fmaxf(mx, wv[k]);
    }
    float sum = 0.f;
#pragma unroll
    for (int k = 0; k < TOPK; ++k) { wv[k] = expf(wv[k] - mx); sum += wv[k]; }
#pragma unroll
    for (int k = 0; k < TOPK; ++k) w_out[t * TOPK + k] = wv[k] / sum;
  }
}

// out[b][l][c] = sum_k w[b][k] * bf2f(U[b][(l+idx_k)%L][c])   (fp32 out)
__global__ __launch_bounds__(256) void gather_out(
    const short* __restrict__ U, const float* __restrict__ w,
    const int* __restrict__ idx, float* __restrict__ out)
{
  const int b = blockIdx.y;
  __shared__ float ww[8];
  __shared__ int   ii[8];
  if (threadIdx.x < TOPK) { ww[threadIdx.x] = w[b * TOPK + threadIdx.x]; ii[threadIdx.x] = idx[threadIdx.x]; }
  __syncthreads();
  const int l = blockIdx.x * 4 + (threadIdx.x >> 6);
  const int c = (threadIdx.x & 63) * 8;
  const short* ub = U + (size_t)b * Ll * Dd;
  float a[8] = {};
#pragma unroll
  for (int k = 0; k < TOPK; ++k) {
    const short8 vv = *(const short8*)&ub[(size_t)((l + ii[k]) & (Ll - 1)) * Dd + c];
    const float wk = ww[k];
#pragma unroll
    for (int e = 0; e < 8; ++e) a[e] = fmaf(wk, bf2f(vv[e]), a[e]);
  }
  float* op = &out[((size_t)b * Ll + l) * Dd + c];
  *(float4*)op       = make_float4(a[0], a[1], a[2], a[3]);
  *(float4*)(op + 4) = make_float4(a[4], a[5], a[6], a[7]);
}

}  // namespace

extern "C" void kernel_launch(void* const* d_in, const int* in_sizes, int n_in,
                              void* d_out, int out_size, void* d_ws, size_t ws_size,
                              hipStream_t stream)
{
  const float* Q   = (const float*)d_in[0];
  const float* K   = (const float*)d_in[1];
  const float* V   = (const float*)d_in[2];
  const float* WQ  = (const float*)d_in[4];
  const float* WK  = (const float*)d_in[5];
  const float* WV  = (const float*)d_in[6];
  const float* Wfc = (const float*)d_in[7];
  float* out = (float*)d_out;

  char* ws = (char*)d_ws;
  const size_t SB = (size_t)Bb * Ll * Dd * sizeof(short);   // 16 MiB
  short* T    = (short*)(ws);
  short* U    = (short*)(ws + 1 * SB);
  short* wqb  = (short*)(ws + 2 * SB);
  short* wkb  = wqb + 512 * 512;
  short* wvb  = wkb + 512 * 512;
  short* wtf  = wvb + 512 * 512;
  short* Gt   = wtf + 512 * 512;
  short* Ht   = Gt  + 512 * 512;
  float* mv   = (float*)(Ht + 512 * 512);
  float* w    = mv + Bb * Ll;
  int*   idx  = (int*)(w + 128);

  // weights -> bf16 (wqb/wkb/wvb straight, wtf = Wfc^T), zero mv
  prep<<<dim3(16, 16, 4), 256, 0, stream>>>(WQ, WK, WV, Wfc, wqb, wkb, wvb, wtf, mv);

  // Gt[n][k] = sum_e Wk[n][e]*Wq[k][e] ; Ht[n][k] = sum_e Wfc[e][n]*Wv[k][e]
  g64<0><<<32, 256, 0, stream>>>(wkb, wtf, wqb, wvb, Gt, Ht);

  // T = bf16(Q @ Gt^T) ; U = bf16(V @ Ht^T)
  g64<1><<<dim3(512, 1, 2), 256, 0, stream>>>(Q, V, Gt, Ht, T, U);

  // mv[b][(t-s)%L] += T[b,t,:] · bf16(K[b,s,:])   (256^2 tiles, fused fp32-K)
  corr_gemm<<<256, 1024, 0, stream>>>(T, K, mv);

  topk_softmax<<<1, 1024, 0, stream>>>(mv, idx, w);

  // out[b,l,:] = sum_k w_k * U[b,(l+d_k)%L,:]
  gather_out<<<dim3(Ll / 4, Bb), 256, 0, stream>>>(U, w, idx, out);
}